// Round 1
// baseline (395.036 us; speedup 1.0000x reference)
//
#include <hip/hip_runtime.h>
#include <stdint.h>

// ---- problem constants ----
#define BATCH 4
#define S_LEN 2048
#define D_DIM 1024
#define NH 16
#define HD 64
#define M_ROWS (BATCH * S_LEN)  // 8192

using u16 = unsigned short;
typedef __attribute__((ext_vector_type(8))) __bf16 bf16x8;
typedef __attribute__((ext_vector_type(4))) float f32x4;
typedef __attribute__((ext_vector_type(8))) unsigned short u16x8;

__device__ __forceinline__ u16 f2bf(float f) {
  unsigned u = __builtin_bit_cast(unsigned, f);
  u += 0x7fffu + ((u >> 16) & 1u);  // RNE
  return (u16)(u >> 16);
}

// ---------------- fp32 -> bf16 conversion (vectorized) ----------------
__global__ void cvt_bf16_kernel(const float* __restrict__ in, u16* __restrict__ out, int n4) {
  int i = blockIdx.x * blockDim.x + threadIdx.x;
  if (i < n4) {
    float4 v = ((const float4*)in)[i];
    ushort4 o;
    o.x = f2bf(v.x); o.y = f2bf(v.y); o.z = f2bf(v.z); o.w = f2bf(v.w);
    ((ushort4*)out)[i] = o;
  }
}

// ---------------- bf16 GEMM: C[m,n] = sum_k A[m,k]*Bt[n,k] + bias[n] ----------------
// MODE 0: output bf16 into [B,H,S,HD] head layout (for Q/K/V)
// MODE 1: output fp32 into [M,N] row-major (final projection)
template<int MODE>
__global__ __launch_bounds__(256)
void gemm_bt_kernel(const u16* __restrict__ A, const u16* __restrict__ Bt,
                    const float* __restrict__ bias, void* __restrict__ Cout,
                    int M, int N, int K) {
  __shared__ __align__(16) u16 As[128 * 64];
  __shared__ __align__(16) u16 Bs[128 * 64];
  const int tid = threadIdx.x;
  const int w = tid >> 6;
  const int lane = tid & 63;
  const int l15 = lane & 15, l4 = lane >> 4;
  const int m0 = blockIdx.y * 128, n0 = blockIdx.x * 128;
  const int wr = (w >> 1) * 64, wc = (w & 1) * 64;

  f32x4 acc[4][4] = {};

  for (int k0 = 0; k0 < K; k0 += 64) {
    __syncthreads();
    // stage A,B tiles (128x64 bf16 each) via global_load_lds, 16B/lane.
    // LDS kept linear; source address pre-swizzled: granule g at row holds
    // global granule g ^ (row&7). Read side applies the same XOR.
#pragma unroll
    for (int i = 0; i < 4; ++i) {
      int chunk = w * 4 + i;                 // 0..15, 1KB chunks
      int o = chunk * 1024 + lane * 16;      // byte offset in 16KB tile
      int row = o >> 7;                      // /128B per row (64 bf16)
      int g = (o >> 4) & 7;                  // 16B granule within row
      int gs = g ^ (row & 7);
      const u16* gA = A + (size_t)(m0 + row) * K + k0 + gs * 8;
      const u16* gB = Bt + (size_t)(n0 + row) * K + k0 + gs * 8;
      __builtin_amdgcn_global_load_lds((const __attribute__((address_space(1))) void*)gA,
                                       (__attribute__((address_space(3))) void*)(As + chunk * 512),
                                       16, 0, 0);
      __builtin_amdgcn_global_load_lds((const __attribute__((address_space(1))) void*)gB,
                                       (__attribute__((address_space(3))) void*)(Bs + chunk * 512),
                                       16, 0, 0);
    }
    __syncthreads();

    bf16x8 a[4][2];
#pragma unroll
    for (int mb = 0; mb < 4; ++mb) {
#pragma unroll
      for (int ks = 0; ks < 2; ++ks) {
        int row = wr + mb * 16 + l15;
        int gsw = (ks * 4 + l4) ^ (row & 7);
        a[mb][ks] = *(const bf16x8*)(As + row * 64 + gsw * 8);
      }
    }
#pragma unroll
    for (int nb = 0; nb < 4; ++nb) {
      int row = wc + nb * 16 + l15;
      int g0 = (0 + l4) ^ (row & 7);
      int g1 = (4 + l4) ^ (row & 7);
      bf16x8 b0 = *(const bf16x8*)(Bs + row * 64 + g0 * 8);
      bf16x8 b1 = *(const bf16x8*)(Bs + row * 64 + g1 * 8);
#pragma unroll
      for (int mb = 0; mb < 4; ++mb) {
        acc[mb][nb] = __builtin_amdgcn_mfma_f32_16x16x32_bf16(a[mb][0], b0, acc[mb][nb], 0, 0, 0);
        acc[mb][nb] = __builtin_amdgcn_mfma_f32_16x16x32_bf16(a[mb][1], b1, acc[mb][nb], 0, 0, 0);
      }
    }
  }

  // epilogue: C/D layout col=lane&15, row=(lane>>4)*4+reg  [m89]
#pragma unroll
  for (int mb = 0; mb < 4; ++mb) {
#pragma unroll
    for (int nb = 0; nb < 4; ++nb) {
#pragma unroll
      for (int r = 0; r < 4; ++r) {
        int m = m0 + wr + mb * 16 + l4 * 4 + r;
        int n = n0 + wc + nb * 16 + l15;
        float v = acc[mb][nb][r] + bias[n];
        if (MODE == 0) {
          int bb = m >> 11;       // / S_LEN
          int ss = m & (S_LEN - 1);
          int hh = n >> 6;        // / HD
          int hd = n & (HD - 1);
          ((u16*)Cout)[(((size_t)bb * NH + hh) * S_LEN + ss) * HD + hd] = f2bf(v);
        } else {
          ((float*)Cout)[(size_t)m * N + n] = v;
        }
      }
    }
  }
}

// ---------------- causal flash attention ----------------
// Q,K,V: [B*H][S][HD] bf16.  ctx out: [B*S][D] bf16 (row b*S+s, col h*HD+hd).
// Grid: x = S/64 q-blocks, y = B*H. 4 waves; wave w owns q rows w*16..w*16+15.
__global__ __launch_bounds__(256)
void attn_kernel(const u16* __restrict__ Q, const u16* __restrict__ Kg,
                 const u16* __restrict__ Vg, u16* __restrict__ ctx) {
  __shared__ __align__(16) u16 Ks[64 * 72];      // K tile [key][d], padded
  __shared__ __align__(16) u16 Vt[64 * 72];      // V^T tile [d][key], padded
  __shared__ __align__(16) u16 Ps[4][16 * 72];   // per-wave P [q][key], padded

  const int tid = threadIdx.x;
  const int w = tid >> 6, lane = tid & 63;
  const int l15 = lane & 15, l4 = lane >> 4;
  const int qb = blockIdx.x, bh = blockIdx.y;
  const size_t base = (size_t)bh * S_LEN * HD;

  // Q fragments: lane holds Q[qrow][ks*32 + l4*8 .. +8]
  bf16x8 qf[2];
  {
    int qrow = qb * 64 + w * 16 + l15;
    #pragma unroll
    for (int ks = 0; ks < 2; ++ks)
      qf[ks] = *(const bf16x8*)(Q + base + (size_t)qrow * HD + ks * 32 + l4 * 8);
  }

  float mrun[4], lrun[4];
  f32x4 acc[4] = {};
#pragma unroll
  for (int r = 0; r < 4; ++r) { mrun[r] = -1e30f; lrun[r] = 0.f; }

  const int nkt = qb + 1;
  for (int kt = 0; kt < nkt; ++kt) {
    __syncthreads();
    {   // stage K tile and transposed V tile
      int row = tid >> 2;            // 0..63
      int c0 = (tid & 3) * 16;
      const u16* gk = Kg + base + (size_t)(kt * 64 + row) * HD + c0;
      u16x8 kv0 = *(const u16x8*)gk;
      u16x8 kv1 = *(const u16x8*)(gk + 8);
      *(u16x8*)&Ks[row * 72 + c0] = kv0;
      *(u16x8*)&Ks[row * 72 + c0 + 8] = kv1;
      const u16* gv = Vg + base + (size_t)(kt * 64 + row) * HD + c0;
      u16x8 vv0 = *(const u16x8*)gv;
      u16x8 vv1 = *(const u16x8*)(gv + 8);
#pragma unroll
      for (int j = 0; j < 8; ++j) {
        Vt[(c0 + j) * 72 + row] = vv0[j];
        Vt[(c0 + 8 + j) * 72 + row] = vv1[j];
      }
    }
    __syncthreads();

    // scores: sc[f] holds S[q = l4*4+r][key = f*16+l15]
    f32x4 sc[4];
#pragma unroll
    for (int f = 0; f < 4; ++f) {
      bf16x8 k0 = *(const bf16x8*)(Ks + (f * 16 + l15) * 72 + 0 + l4 * 8);
      bf16x8 k1 = *(const bf16x8*)(Ks + (f * 16 + l15) * 72 + 32 + l4 * 8);
      f32x4 z = {};
      z = __builtin_amdgcn_mfma_f32_16x16x32_bf16(qf[0], k0, z, 0, 0, 0);
      sc[f] = __builtin_amdgcn_mfma_f32_16x16x32_bf16(qf[1], k1, z, 0, 0, 0);
    }

    const bool diag = (kt == qb);
    float s[4][4];
#pragma unroll
    for (int f = 0; f < 4; ++f) {
#pragma unroll
      for (int r = 0; r < 4; ++r) {
        float v = sc[f][r] * 0.125f;  // 1/sqrt(64)
        if (diag) {
          int keyl = f * 16 + l15;
          int ql = w * 16 + l4 * 4 + r;
          if (keyl > ql) v = -1e30f;
        }
        s[f][r] = v;
      }
    }

    // online softmax; row-reduce across the 16 lanes sharing l4
    float p[4][4];
#pragma unroll
    for (int r = 0; r < 4; ++r) {
      float tm = fmaxf(fmaxf(s[0][r], s[1][r]), fmaxf(s[2][r], s[3][r]));
      tm = fmaxf(tm, __shfl_xor(tm, 1));
      tm = fmaxf(tm, __shfl_xor(tm, 2));
      tm = fmaxf(tm, __shfl_xor(tm, 4));
      tm = fmaxf(tm, __shfl_xor(tm, 8));
      float mnew = fmaxf(mrun[r], tm);
      float rs = __expf(mrun[r] - mnew);
      mrun[r] = mnew;
      float sum = 0.f;
#pragma unroll
      for (int f = 0; f < 4; ++f) { p[f][r] = __expf(s[f][r] - mnew); sum += p[f][r]; }
      sum += __shfl_xor(sum, 1);
      sum += __shfl_xor(sum, 2);
      sum += __shfl_xor(sum, 4);
      sum += __shfl_xor(sum, 8);
      lrun[r] = lrun[r] * rs + sum;
#pragma unroll
      for (int fd = 0; fd < 4; ++fd) acc[fd][r] *= rs;
    }

    // P -> bf16 A-fragment layout via per-wave LDS (in-wave DS ops are ordered)
    u16* Pw = &Ps[w][0];
#pragma unroll
    for (int f = 0; f < 4; ++f)
#pragma unroll
      for (int r = 0; r < 4; ++r)
        Pw[(l4 * 4 + r) * 72 + f * 16 + l15] = f2bf(p[f][r]);

    bf16x8 pa0 = *(const bf16x8*)(Pw + l15 * 72 + 0 + l4 * 8);
    bf16x8 pa1 = *(const bf16x8*)(Pw + l15 * 72 + 32 + l4 * 8);

#pragma unroll
    for (int fd = 0; fd < 4; ++fd) {
      bf16x8 v0 = *(const bf16x8*)(Vt + (fd * 16 + l15) * 72 + 0 + l4 * 8);
      bf16x8 v1 = *(const bf16x8*)(Vt + (fd * 16 + l15) * 72 + 32 + l4 * 8);
      acc[fd] = __builtin_amdgcn_mfma_f32_16x16x32_bf16(pa0, v0, acc[fd], 0, 0, 0);
      acc[fd] = __builtin_amdgcn_mfma_f32_16x16x32_bf16(pa1, v1, acc[fd], 0, 0, 0);
    }
  }

  const int b = bh >> 4, h = bh & (NH - 1);
#pragma unroll
  for (int fd = 0; fd < 4; ++fd) {
#pragma unroll
    for (int r = 0; r < 4; ++r) {
      int srow = qb * 64 + w * 16 + l4 * 4 + r;
      float o = acc[fd][r] / lrun[r];
      ctx[((size_t)b * S_LEN + srow) * D_DIM + h * HD + fd * 16 + l15] = f2bf(o);
    }
  }
}

// ---------------- host launcher ----------------
extern "C" void kernel_launch(void* const* d_in, const int* in_sizes, int n_in,
                              void* d_out, int out_size, void* d_ws, size_t ws_size,
                              hipStream_t stream) {
  const float* x  = (const float*)d_in[0];
  const float* Wq = (const float*)d_in[1];
  const float* bq = (const float*)d_in[2];
  const float* Wk = (const float*)d_in[3];
  const float* bk = (const float*)d_in[4];
  const float* Wv = (const float*)d_in[5];
  const float* bv = (const float*)d_in[6];
  const float* Wo = (const float*)d_in[7];
  const float* bo = (const float*)d_in[8];

  char* ws = (char*)d_ws;
  const size_t MB = 1024 * 1024;
  u16* xb   = (u16*)(ws + 0);        // 16 MB  [M, D] bf16
  u16* Wqb  = (u16*)(ws + 16 * MB);  // 2 MB each
  u16* Wkb  = (u16*)(ws + 18 * MB);
  u16* Wvb  = (u16*)(ws + 20 * MB);
  u16* Wob  = (u16*)(ws + 22 * MB);
  u16* Qb   = (u16*)(ws + 24 * MB);  // 16 MB  [B,H,S,HD] bf16
  u16* Kb   = (u16*)(ws + 40 * MB);
  u16* Vb   = (u16*)(ws + 56 * MB);
  u16* ctxb = xb;                    // reuse xb after QKV GEMMs

  // conversions
  cvt_bf16_kernel<<<(M_ROWS * D_DIM / 4 + 255) / 256, 256, 0, stream>>>(x, xb, M_ROWS * D_DIM / 4);
  cvt_bf16_kernel<<<(D_DIM * D_DIM / 4 + 255) / 256, 256, 0, stream>>>(Wq, Wqb, D_DIM * D_DIM / 4);
  cvt_bf16_kernel<<<(D_DIM * D_DIM / 4 + 255) / 256, 256, 0, stream>>>(Wk, Wkb, D_DIM * D_DIM / 4);
  cvt_bf16_kernel<<<(D_DIM * D_DIM / 4 + 255) / 256, 256, 0, stream>>>(Wv, Wvb, D_DIM * D_DIM / 4);
  cvt_bf16_kernel<<<(D_DIM * D_DIM / 4 + 255) / 256, 256, 0, stream>>>(Wo, Wob, D_DIM * D_DIM / 4);

  // QKV projections (write head layout)
  dim3 gg(D_DIM / 128, M_ROWS / 128);
  gemm_bt_kernel<0><<<gg, 256, 0, stream>>>(xb, Wqb, bq, Qb, M_ROWS, D_DIM, D_DIM);
  gemm_bt_kernel<0><<<gg, 256, 0, stream>>>(xb, Wkb, bk, Kb, M_ROWS, D_DIM, D_DIM);
  gemm_bt_kernel<0><<<gg, 256, 0, stream>>>(xb, Wvb, bv, Vb, M_ROWS, D_DIM, D_DIM);

  // attention
  attn_kernel<<<dim3(S_LEN / 64, BATCH * NH), 256, 0, stream>>>(Qb, Kb, Vb, ctxb);

  // output projection (fp32 out)
  gemm_bt_kernel<1><<<gg, 256, 0, stream>>>(ctxb, Wob, bo, (float*)d_out, M_ROWS, D_DIM, D_DIM);
}

// Round 4
// 394.686 us; speedup vs baseline: 1.0009x; 1.0009x over previous
//
#include <hip/hip_runtime.h>
#include <stdint.h>

// ---- problem constants ----
#define BATCH 4
#define S_LEN 2048
#define D_DIM 1024
#define NH 16
#define HD 64
#define M_ROWS (BATCH * S_LEN)  // 8192

using u16 = unsigned short;
typedef __attribute__((ext_vector_type(8))) __bf16 bf16x8;
typedef __attribute__((ext_vector_type(4))) float f32x4;
typedef __attribute__((ext_vector_type(8))) unsigned short u16x8;

__device__ __forceinline__ u16 f2bf(float f) {
  unsigned u = __builtin_bit_cast(unsigned, f);
  u += 0x7fffu + ((u >> 16) & 1u);  // RNE
  return (u16)(u >> 16);
}

// ---------------- fp32 -> bf16 conversion ----------------
__global__ void cvt_bf16_kernel(const float* __restrict__ in, u16* __restrict__ out, int n4) {
  int i = blockIdx.x * blockDim.x + threadIdx.x;
  if (i < n4) {
    float4 v = ((const float4*)in)[i];
    ushort4 o;
    o.x = f2bf(v.x); o.y = f2bf(v.y); o.z = f2bf(v.z); o.w = f2bf(v.w);
    ((ushort4*)out)[i] = o;
  }
}

// ---------------- bf16 GEMM: C = (A*Bt^T + bias) * scale ----------------
template<int MODE>  // 0: bf16 out in [B,H,S,HD]; 1: fp32 out [M,N]
__global__ __launch_bounds__(256)
void gemm_bt_kernel(const u16* __restrict__ A, const u16* __restrict__ Bt,
                    const float* __restrict__ bias, void* __restrict__ Cout,
                    int M, int N, int K, float scale) {
  __shared__ __align__(16) u16 As[128 * 64];
  __shared__ __align__(16) u16 Bs[128 * 64];
  const int tid = threadIdx.x;
  const int w = tid >> 6;
  const int lane = tid & 63;
  const int l15 = lane & 15, l4 = lane >> 4;
  const int m0 = blockIdx.y * 128, n0 = blockIdx.x * 128;
  const int wr = (w >> 1) * 64, wc = (w & 1) * 64;

  f32x4 acc[4][4] = {};

  for (int k0 = 0; k0 < K; k0 += 64) {
    __syncthreads();
#pragma unroll
    for (int i = 0; i < 4; ++i) {
      int chunk = w * 4 + i;
      int o = chunk * 1024 + lane * 16;
      int row = o >> 7;
      int g = (o >> 4) & 7;
      int gs = g ^ (row & 7);
      const u16* gA = A + (size_t)(m0 + row) * K + k0 + gs * 8;
      const u16* gB = Bt + (size_t)(n0 + row) * K + k0 + gs * 8;
      __builtin_amdgcn_global_load_lds((const __attribute__((address_space(1))) void*)gA,
                                       (__attribute__((address_space(3))) void*)(As + chunk * 512),
                                       16, 0, 0);
      __builtin_amdgcn_global_load_lds((const __attribute__((address_space(1))) void*)gB,
                                       (__attribute__((address_space(3))) void*)(Bs + chunk * 512),
                                       16, 0, 0);
    }
    __syncthreads();

    bf16x8 a[4][2];
#pragma unroll
    for (int mb = 0; mb < 4; ++mb) {
#pragma unroll
      for (int ks = 0; ks < 2; ++ks) {
        int row = wr + mb * 16 + l15;
        int gsw = (ks * 4 + l4) ^ (row & 7);
        a[mb][ks] = *(const bf16x8*)(As + row * 64 + gsw * 8);
      }
    }
#pragma unroll
    for (int nb = 0; nb < 4; ++nb) {
      int row = wc + nb * 16 + l15;
      int g0 = (0 + l4) ^ (row & 7);
      int g1 = (4 + l4) ^ (row & 7);
      bf16x8 b0 = *(const bf16x8*)(Bs + row * 64 + g0 * 8);
      bf16x8 b1 = *(const bf16x8*)(Bs + row * 64 + g1 * 8);
#pragma unroll
      for (int mb = 0; mb < 4; ++mb) {
        acc[mb][nb] = __builtin_amdgcn_mfma_f32_16x16x32_bf16(a[mb][0], b0, acc[mb][nb], 0, 0, 0);
        acc[mb][nb] = __builtin_amdgcn_mfma_f32_16x16x32_bf16(a[mb][1], b1, acc[mb][nb], 0, 0, 0);
      }
    }
  }

#pragma unroll
  for (int mb = 0; mb < 4; ++mb) {
#pragma unroll
    for (int nb = 0; nb < 4; ++nb) {
#pragma unroll
      for (int r = 0; r < 4; ++r) {
        int m = m0 + wr + mb * 16 + l4 * 4 + r;
        int n = n0 + wc + nb * 16 + l15;
        float v = (acc[mb][nb][r] + bias[n]) * scale;
        if (MODE == 0) {
          int bb = m >> 11;
          int ss = m & (S_LEN - 1);
          int hh = n >> 6;
          int hd = n & (HD - 1);
          ((u16*)Cout)[(((size_t)bb * NH + hh) * S_LEN + ss) * HD + hd] = f2bf(v);
        } else {
          ((float*)Cout)[(size_t)m * N + n] = v;
        }
      }
    }
  }
}

// ---------------- causal flash attention, QBLK=128 ----------------
// Q pre-scaled by 1/8. K: double-buffered LDS via global_load_lds (XOR granule,
// same formula as GEMM staging). V: reg-staged transpose into Vt[d][key]
// (round-1-proven mechanism). All sync = __syncthreads (full fence).
__device__ __forceinline__ void stage_k(const u16* __restrict__ Kg, size_t base, int kt,
                                        u16* Kd, int w, int lane) {
#pragma unroll
  for (int i = 0; i < 2; ++i) {
    int ic = w * 2 + i;
    int c = ic * 64 + lane;                 // 16B chunk index, 0..511
    int row = c >> 3, g = c & 7, gs = g ^ (row & 7);
    __builtin_amdgcn_global_load_lds(
        (const __attribute__((address_space(1))) void*)(Kg + base + (size_t)(kt * 64 + row) * HD + gs * 8),
        (__attribute__((address_space(3))) void*)(Kd + ic * 512), 16, 0, 0);
  }
}

__global__ __launch_bounds__(256)
void attn_kernel(const u16* __restrict__ Q, const u16* __restrict__ Kg,
                 const u16* __restrict__ Vg, u16* __restrict__ ctx) {
  __shared__ __align__(16) u16 Ks[2][64 * 64];   // K double buffer (async staging)
  __shared__ __align__(16) u16 Vt[64 * 72];      // V^T [d][key], stride 72 (144B rows, 16B-aligned)
  __shared__ __align__(16) u16 Ps[4][16 * 72];   // per-wave P [q][key]

  const int tid = threadIdx.x;
  const int w = tid >> 6, lane = tid & 63;
  const int l15 = lane & 15, l4 = lane >> 4;
  const int qb = (gridDim.x - 1) - blockIdx.x;   // long blocks first
  const int bh = blockIdx.y;
  const size_t base = (size_t)bh * S_LEN * HD;
  const int Qbase = qb * 128 + w * 32;

  // V reg-staging addressing (round-1): row = tid>>2, c0 = (tid&3)*16
  const int vrow = tid >> 2;
  const int vc0 = (tid & 3) * 16;

  // Q fragments (pre-scaled by 1/8 in the Q-GEMM)
  bf16x8 qf[2][2];
#pragma unroll
  for (int qm = 0; qm < 2; ++qm)
#pragma unroll
    for (int ks = 0; ks < 2; ++ks)
      qf[qm][ks] = *(const bf16x8*)(Q + base + (size_t)(Qbase + qm * 16 + l15) * HD + ks * 32 + l4 * 8);

  f32x4 acc[2][4] = {};
  float mrun[2][4], lrun[2][4];
#pragma unroll
  for (int qm = 0; qm < 2; ++qm)
#pragma unroll
    for (int r = 0; r < 4; ++r) { mrun[qm][r] = -1e30f; lrun[qm][r] = 0.f; }

  const int nkt = 2 * qb + 2;

  // prologue: K(0) -> LDS (async), V(0) -> regs
  stage_k(Kg, base, 0, Ks[0], w, lane);
  u16x8 vv0, vv1;
  {
    const u16* gv = Vg + base + (size_t)vrow * HD + vc0;
    vv0 = *(const u16x8*)gv;
    vv1 = *(const u16x8*)(gv + 8);
  }

  for (int kt = 0; kt < nkt; ++kt) {
    const int cur = kt & 1;
    const bool more = (kt + 1 < nkt);

    // write V(kt) regs -> Vt (compiler inserts the vmcnt wait on vv0/vv1)
#pragma unroll
    for (int j = 0; j < 8; ++j) {
      Vt[(vc0 + j) * 72 + vrow] = vv0[j];
      Vt[(vc0 + 8 + j) * 72 + vrow] = vv1[j];
    }
    __syncthreads();   // Vt visible; K(kt) landed (drained here or at prev barrier)

    // prefetch next tile: overlaps this iteration's compute
    if (more) {
      stage_k(Kg, base, kt + 1, Ks[cur ^ 1], w, lane);
      const u16* gv = Vg + base + (size_t)((kt + 1) * 64 + vrow) * HD + vc0;
      vv0 = *(const u16x8*)gv;
      vv1 = *(const u16x8*)(gv + 8);
    }

    const u16* Kb = &Ks[cur][0];
    const bool act0 = (kt * 64) <= (Qbase + 15);
    const bool act1 = (kt * 64) <= (Qbase + 31);

    if (act1) {
      // ---- QK^T ----
      f32x4 sc[2][4];
#pragma unroll
      for (int f = 0; f < 4; ++f) {
        int key = f * 16 + l15;
        const u16* kr = Kb + key * 64;
        bf16x8 k0 = *(const bf16x8*)(kr + ((l4 ^ (key & 7)) * 8));
        bf16x8 k1 = *(const bf16x8*)(kr + (((4 + l4) ^ (key & 7)) * 8));
        if (act0) {
          f32x4 z = {};
          z = __builtin_amdgcn_mfma_f32_16x16x32_bf16(qf[0][0], k0, z, 0, 0, 0);
          sc[0][f] = __builtin_amdgcn_mfma_f32_16x16x32_bf16(qf[0][1], k1, z, 0, 0, 0);
        }
        f32x4 z = {};
        z = __builtin_amdgcn_mfma_f32_16x16x32_bf16(qf[1][0], k0, z, 0, 0, 0);
        sc[1][f] = __builtin_amdgcn_mfma_f32_16x16x32_bf16(qf[1][1], k1, z, 0, 0, 0);
      }

      // ---- softmax + P pack + PV (per qm) ----
      bf16x8 pa[2][2];
#pragma unroll
      for (int qm = 0; qm < 2; ++qm) {
        if (qm == 0 && !act0) continue;
        const bool needmask = (kt * 64 + 63) > (Qbase + qm * 16);
        u16* Pw = &Ps[w][0];
#pragma unroll
        for (int r = 0; r < 4; ++r) {
          float v[4];
#pragma unroll
          for (int f = 0; f < 4; ++f) {
            float s = sc[qm][f][r];
            if (needmask) {
              int keyl = f * 16 + l15;
              int qrel = Qbase + qm * 16 + l4 * 4 + r - kt * 64;
              if (keyl > qrel) s = -1e30f;
            }
            v[f] = s;
          }
          float tm = fmaxf(fmaxf(v[0], v[1]), fmaxf(v[2], v[3]));
          tm = fmaxf(tm, __shfl_xor(tm, 1));
          tm = fmaxf(tm, __shfl_xor(tm, 2));
          tm = fmaxf(tm, __shfl_xor(tm, 4));
          tm = fmaxf(tm, __shfl_xor(tm, 8));
          float mnew = fmaxf(mrun[qm][r], tm);
          float rs = __expf(mrun[qm][r] - mnew);
          mrun[qm][r] = mnew;
          float sum = 0.f;
          float p[4];
#pragma unroll
          for (int f = 0; f < 4; ++f) { p[f] = __expf(v[f] - mnew); sum += p[f]; }
          sum += __shfl_xor(sum, 1);
          sum += __shfl_xor(sum, 2);
          sum += __shfl_xor(sum, 4);
          sum += __shfl_xor(sum, 8);
          lrun[qm][r] = lrun[qm][r] * rs + sum;
#pragma unroll
          for (int fd = 0; fd < 4; ++fd) acc[qm][fd][r] *= rs;
#pragma unroll
          for (int f = 0; f < 4; ++f)
            Pw[(l4 * 4 + r) * 72 + f * 16 + l15] = f2bf(p[f]);
        }
        pa[qm][0] = *(const bf16x8*)(Pw + l15 * 72 + l4 * 8);
        pa[qm][1] = *(const bf16x8*)(Pw + l15 * 72 + 32 + l4 * 8);
      }

#pragma unroll
      for (int fd = 0; fd < 4; ++fd) {
        bf16x8 v0 = *(const bf16x8*)(Vt + (fd * 16 + l15) * 72 + l4 * 8);
        bf16x8 v1 = *(const bf16x8*)(Vt + (fd * 16 + l15) * 72 + 32 + l4 * 8);
#pragma unroll
        for (int qm = 0; qm < 2; ++qm) {
          if (qm == 0 && !act0) continue;
          acc[qm][fd] = __builtin_amdgcn_mfma_f32_16x16x32_bf16(pa[qm][0], v0, acc[qm][fd], 0, 0, 0);
          acc[qm][fd] = __builtin_amdgcn_mfma_f32_16x16x32_bf16(pa[qm][1], v1, acc[qm][fd], 0, 0, 0);
        }
      }
    }
    __syncthreads();   // all waves done reading Ks[cur]/Vt; drains prefetch loads
  }

  const int b = bh >> 4, h = bh & (NH - 1);
#pragma unroll
  for (int qm = 0; qm < 2; ++qm)
#pragma unroll
    for (int fd = 0; fd < 4; ++fd)
#pragma unroll
      for (int r = 0; r < 4; ++r) {
        int srow = Qbase + qm * 16 + l4 * 4 + r;
        float o = acc[qm][fd][r] / lrun[qm][r];
        ctx[((size_t)b * S_LEN + srow) * D_DIM + h * HD + fd * 16 + l15] = f2bf(o);
      }
}

// ---------------- host launcher ----------------
extern "C" void kernel_launch(void* const* d_in, const int* in_sizes, int n_in,
                              void* d_out, int out_size, void* d_ws, size_t ws_size,
                              hipStream_t stream) {
  const float* x  = (const float*)d_in[0];
  const float* Wq = (const float*)d_in[1];
  const float* bq = (const float*)d_in[2];
  const float* Wk = (const float*)d_in[3];
  const float* bk = (const float*)d_in[4];
  const float* Wv = (const float*)d_in[5];
  const float* bv = (const float*)d_in[6];
  const float* Wo = (const float*)d_in[7];
  const float* bo = (const float*)d_in[8];

  char* ws = (char*)d_ws;
  const size_t MB = 1024 * 1024;
  u16* xb   = (u16*)(ws + 0);
  u16* Wqb  = (u16*)(ws + 16 * MB);
  u16* Wkb  = (u16*)(ws + 18 * MB);
  u16* Wvb  = (u16*)(ws + 20 * MB);
  u16* Wob  = (u16*)(ws + 22 * MB);
  u16* Qb   = (u16*)(ws + 24 * MB);
  u16* Kb   = (u16*)(ws + 40 * MB);
  u16* Vb   = (u16*)(ws + 56 * MB);
  u16* ctxb = xb;

  cvt_bf16_kernel<<<(M_ROWS * D_DIM / 4 + 255) / 256, 256, 0, stream>>>(x, xb, M_ROWS * D_DIM / 4);
  cvt_bf16_kernel<<<(D_DIM * D_DIM / 4 + 255) / 256, 256, 0, stream>>>(Wq, Wqb, D_DIM * D_DIM / 4);
  cvt_bf16_kernel<<<(D_DIM * D_DIM / 4 + 255) / 256, 256, 0, stream>>>(Wk, Wkb, D_DIM * D_DIM / 4);
  cvt_bf16_kernel<<<(D_DIM * D_DIM / 4 + 255) / 256, 256, 0, stream>>>(Wv, Wvb, D_DIM * D_DIM / 4);
  cvt_bf16_kernel<<<(D_DIM * D_DIM / 4 + 255) / 256, 256, 0, stream>>>(Wo, Wob, D_DIM * D_DIM / 4);

  dim3 gg(D_DIM / 128, M_ROWS / 128);
  gemm_bt_kernel<0><<<gg, 256, 0, stream>>>(xb, Wqb, bq, Qb, M_ROWS, D_DIM, D_DIM, 0.125f);
  gemm_bt_kernel<0><<<gg, 256, 0, stream>>>(xb, Wkb, bk, Kb, M_ROWS, D_DIM, D_DIM, 1.0f);
  gemm_bt_kernel<0><<<gg, 256, 0, stream>>>(xb, Wvb, bv, Vb, M_ROWS, D_DIM, D_DIM, 1.0f);

  attn_kernel<<<dim3(S_LEN / 128, BATCH * NH), 256, 0, stream>>>(Qb, Kb, Vb, ctxb);

  gemm_bt_kernel<1><<<gg, 256, 0, stream>>>(ctxb, Wob, bo, (float*)d_out, M_ROWS, D_DIM, D_DIM, 1.0f);
}

// Round 6
// 296.594 us; speedup vs baseline: 1.3319x; 1.3307x over previous
//
#include <hip/hip_runtime.h>
#include <stdint.h>

// ---- problem constants ----
#define BATCH 4
#define S_LEN 2048
#define D_DIM 1024
#define NH 16
#define HD 64
#define M_ROWS (BATCH * S_LEN)  // 8192

using u16 = unsigned short;
typedef __attribute__((ext_vector_type(8))) __bf16 bf16x8;
typedef __attribute__((ext_vector_type(4))) float f32x4;
typedef __attribute__((ext_vector_type(16))) float f32x16;
typedef __attribute__((ext_vector_type(8))) unsigned short u16x8;

__device__ __forceinline__ u16 f2bf(float f) {
  unsigned u = __builtin_bit_cast(unsigned, f);
  u += 0x7fffu + ((u >> 16) & 1u);  // RNE
  return (u16)(u >> 16);
}
__device__ __forceinline__ unsigned pk2(float lo, float hi) {
  return (unsigned)f2bf(lo) | ((unsigned)f2bf(hi) << 16);
}

// ---------------- fp32 -> bf16 conversion ----------------
__global__ void cvt_bf16_kernel(const float* __restrict__ in, u16* __restrict__ out, int n4) {
  int i = blockIdx.x * blockDim.x + threadIdx.x;
  if (i < n4) {
    float4 v = ((const float4*)in)[i];
    ushort4 o;
    o.x = f2bf(v.x); o.y = f2bf(v.y); o.z = f2bf(v.z); o.w = f2bf(v.w);
    ((ushort4*)out)[i] = o;
  }
}

// ---------------- bf16 GEMM: C = (A*Bt^T + bias) * scale ----------------
template<int MODE>  // 0: bf16 out in [B,H,S,HD]; 1: fp32 out [M,N]
__global__ __launch_bounds__(256)
void gemm_bt_kernel(const u16* __restrict__ A, const u16* __restrict__ Bt,
                    const float* __restrict__ bias, void* __restrict__ Cout,
                    int M, int N, int K, float scale) {
  __shared__ __align__(16) u16 As[128 * 64];
  __shared__ __align__(16) u16 Bs[128 * 64];
  const int tid = threadIdx.x;
  const int w = tid >> 6;
  const int lane = tid & 63;
  const int l15 = lane & 15, l4 = lane >> 4;
  const int m0 = blockIdx.y * 128, n0 = blockIdx.x * 128;
  const int wr = (w >> 1) * 64, wc = (w & 1) * 64;

  f32x4 acc[4][4] = {};

  for (int k0 = 0; k0 < K; k0 += 64) {
    __syncthreads();
#pragma unroll
    for (int i = 0; i < 4; ++i) {
      int chunk = w * 4 + i;
      int o = chunk * 1024 + lane * 16;
      int row = o >> 7;
      int g = (o >> 4) & 7;
      int gs = g ^ (row & 7);
      const u16* gA = A + (size_t)(m0 + row) * K + k0 + gs * 8;
      const u16* gB = Bt + (size_t)(n0 + row) * K + k0 + gs * 8;
      __builtin_amdgcn_global_load_lds((const __attribute__((address_space(1))) void*)gA,
                                       (__attribute__((address_space(3))) void*)(As + chunk * 512),
                                       16, 0, 0);
      __builtin_amdgcn_global_load_lds((const __attribute__((address_space(1))) void*)gB,
                                       (__attribute__((address_space(3))) void*)(Bs + chunk * 512),
                                       16, 0, 0);
    }
    __syncthreads();

    bf16x8 a[4][2];
#pragma unroll
    for (int mb = 0; mb < 4; ++mb) {
#pragma unroll
      for (int ks = 0; ks < 2; ++ks) {
        int row = wr + mb * 16 + l15;
        int gsw = (ks * 4 + l4) ^ (row & 7);
        a[mb][ks] = *(const bf16x8*)(As + row * 64 + gsw * 8);
      }
    }
#pragma unroll
    for (int nb = 0; nb < 4; ++nb) {
      int row = wc + nb * 16 + l15;
      int g0 = (0 + l4) ^ (row & 7);
      int g1 = (4 + l4) ^ (row & 7);
      bf16x8 b0 = *(const bf16x8*)(Bs + row * 64 + g0 * 8);
      bf16x8 b1 = *(const bf16x8*)(Bs + row * 64 + g1 * 8);
#pragma unroll
      for (int mb = 0; mb < 4; ++mb) {
        acc[mb][nb] = __builtin_amdgcn_mfma_f32_16x16x32_bf16(a[mb][0], b0, acc[mb][nb], 0, 0, 0);
        acc[mb][nb] = __builtin_amdgcn_mfma_f32_16x16x32_bf16(a[mb][1], b1, acc[mb][nb], 0, 0, 0);
      }
    }
  }

#pragma unroll
  for (int mb = 0; mb < 4; ++mb) {
#pragma unroll
    for (int nb = 0; nb < 4; ++nb) {
#pragma unroll
      for (int r = 0; r < 4; ++r) {
        int m = m0 + wr + mb * 16 + l4 * 4 + r;
        int n = n0 + wc + nb * 16 + l15;
        float v = (acc[mb][nb][r] + bias[n]) * scale;
        if (MODE == 0) {
          int bb = m >> 11;
          int ss = m & (S_LEN - 1);
          int hh = n >> 6;
          int hd = n & (HD - 1);
          ((u16*)Cout)[(((size_t)bb * NH + hh) * S_LEN + ss) * HD + hd] = f2bf(v);
        } else {
          ((float*)Cout)[(size_t)m * N + n] = v;
        }
      }
    }
  }
}

// ---------------- causal flash attention, swapped QK^T, 32x32 MFMA ----------------
// Per wave: 32 queries. S^T = mfma(K, Q): lane holds S[key(r,hi)][q=l31].
// Softmax in-register (one shfl_xor(32) pair-reduce). P A-frags via manual
// bf16 pack + shfl_xor(32) half-exchange (proven primitives only).
__device__ __forceinline__ void stage_k(const u16* __restrict__ Kg, size_t base, int kt,
                                        u16* Kd, int w, int lane) {
#pragma unroll
  for (int i = 0; i < 2; ++i) {
    int ic = w * 2 + i;
    int c = ic * 64 + lane;                 // 16B chunk index, 0..511
    int row = c >> 3, g = c & 7, gs = g ^ (row & 7);
    __builtin_amdgcn_global_load_lds(
        (const __attribute__((address_space(1))) void*)(Kg + base + (size_t)(kt * 64 + row) * HD + gs * 8),
        (__attribute__((address_space(3))) void*)(Kd + ic * 512), 16, 0, 0);
  }
}

// build two A-frags (keys 0..15 and 16..31 of a 32-key half) from st
__device__ __forceinline__ void pfrag(const f32x16& st, int hi, bf16x8& fa, bf16x8& fb) {
  unsigned c0 = pk2(st[0], st[1]),   c1 = pk2(st[2], st[3]);
  unsigned c2 = pk2(st[4], st[5]),   c3 = pk2(st[6], st[7]);
  unsigned c4 = pk2(st[8], st[9]),   c5 = pk2(st[10], st[11]);
  unsigned c6 = pk2(st[12], st[13]), c7 = pk2(st[14], st[15]);
  unsigned p0 = __shfl_xor(c0, 32), p1 = __shfl_xor(c1, 32);
  unsigned p2 = __shfl_xor(c2, 32), p3 = __shfl_xor(c3, 32);
  unsigned p4 = __shfl_xor(c4, 32), p5 = __shfl_xor(c5, 32);
  unsigned p6 = __shfl_xor(c6, 32), p7 = __shfl_xor(c7, 32);
  union { unsigned u[4]; bf16x8 v; } a, b;
  a.u[0] = hi ? p2 : c0; a.u[1] = hi ? p3 : c1;
  a.u[2] = hi ? c2 : p0; a.u[3] = hi ? c3 : p1;
  b.u[0] = hi ? p6 : c4; b.u[1] = hi ? p7 : c5;
  b.u[2] = hi ? c6 : p4; b.u[3] = hi ? c7 : p5;
  fa = a.v; fb = b.v;
}

__global__ __launch_bounds__(256)
void attn_kernel(const u16* __restrict__ Q, const u16* __restrict__ Kg,
                 const u16* __restrict__ Vg, u16* __restrict__ ctx) {
  __shared__ __align__(16) u16 Ks[2][64 * 64];   // K double buffer
  __shared__ __align__(16) u16 Vt[64 * 64];      // V^T [d][key], granule-XOR swizzled

  const int tid = threadIdx.x;
  const int w = tid >> 6, lane = tid & 63;
  const int l31 = lane & 31, hi = lane >> 5;
  const int hi4 = hi * 4, hi8 = hi * 8;
  const int qb = (gridDim.x - 1) - blockIdx.x;   // long blocks first
  const int bh = blockIdx.y;
  const size_t base = (size_t)bh * S_LEN * HD;
  const int Qw = qb * 128 + w * 32;
  const int q_g = Qw + l31;

  const int vrow = tid >> 2;          // key row this thread transposes
  const int vc0 = (tid & 3) * 16;     // d-range start

  // Q fragments (pre-scaled by 1/8): qf[step] = Q[q_g][step*16 + hi8 .. +8]
  bf16x8 qf[4];
#pragma unroll
  for (int step = 0; step < 4; ++step)
    qf[step] = *(const bf16x8*)(Q + base + (size_t)q_g * HD + step * 16 + hi8);

  f32x16 oacc0 = {}, oacc1 = {};   // O[q][d]: col=d=l31 (+32), row q=(r&3)+8*(r>>2)+hi4
  float mrun = -1e30f, lrun = 0.f;

  const int nkt = 2 * qb + 2;

  stage_k(Kg, base, 0, Ks[0], w, lane);
  u16x8 vv0, vv1;
  {
    const u16* gv = Vg + base + (size_t)vrow * HD + vc0;
    vv0 = *(const u16x8*)gv;
    vv1 = *(const u16x8*)(gv + 8);
  }

  for (int kt = 0; kt < nkt; ++kt) {
    const int cur = kt & 1;
    const bool more = (kt + 1 < nkt);

    // V(kt) regs -> Vt (transpose), granule XOR by (d>>2)&7
#pragma unroll
    for (int j = 0; j < 8; ++j) {
      int d0 = vc0 + j;
      Vt[d0 * 64 + (((vrow >> 3) ^ ((d0 >> 2) & 7)) << 3) + (vrow & 7)] = vv0[j];
      int d1 = vc0 + 8 + j;
      Vt[d1 * 64 + (((vrow >> 3) ^ ((d1 >> 2) & 7)) << 3) + (vrow & 7)] = vv1[j];
    }
    __syncthreads();   // Vt + Ks[cur] ready

    if (more) {
      stage_k(Kg, base, kt + 1, Ks[cur ^ 1], w, lane);
      const u16* gv = Vg + base + (size_t)((kt + 1) * 64 + vrow) * HD + vc0;
      vv0 = *(const u16x8*)gv;
      vv1 = *(const u16x8*)(gv + 8);
    }

    const u16* Kb = &Ks[cur][0];

    if (kt * 64 <= Qw + 31) {
      // ---- swapped QK^T: st[key][q] ----
      f32x16 st0 = {}, st1 = {};
#pragma unroll
      for (int step = 0; step < 4; ++step) {
        int r0 = l31, r1 = 32 + l31;
        bf16x8 kf0 = *(const bf16x8*)(Kb + r0 * 64 + (((step * 2 + hi) ^ (r0 & 7)) << 3));
        bf16x8 kf1 = *(const bf16x8*)(Kb + r1 * 64 + (((step * 2 + hi) ^ (r1 & 7)) << 3));
        st0 = __builtin_amdgcn_mfma_f32_32x32x16_bf16(kf0, qf[step], st0, 0, 0, 0);
        st1 = __builtin_amdgcn_mfma_f32_32x32x16_bf16(kf1, qf[step], st1, 0, 0, 0);
      }

      // ---- causal mask ----
      if (kt * 64 + 63 > Qw) {
#pragma unroll
        for (int r = 0; r < 16; ++r) {
          int key0 = kt * 64 + hi4 + (r & 3) + 8 * (r >> 2);
          if (key0 > q_g) st0[r] = -1e30f;
          if (key0 + 32 > q_g) st1[r] = -1e30f;
        }
      }

      // ---- in-register softmax (row = query = l31; partner lane l31+32) ----
      float tm = -1e30f;
#pragma unroll
      for (int r = 0; r < 16; ++r) { tm = fmaxf(tm, st0[r]); tm = fmaxf(tm, st1[r]); }
      tm = fmaxf(tm, __shfl_xor(tm, 32));
      float mnew = fmaxf(mrun, tm);
      float rs = __expf(mrun - mnew);
      mrun = mnew;
      float sum = 0.f;
#pragma unroll
      for (int r = 0; r < 16; ++r) {
        st0[r] = __expf(st0[r] - mnew); sum += st0[r];
        st1[r] = __expf(st1[r] - mnew); sum += st1[r];
      }
      sum += __shfl_xor(sum, 32);
      lrun = lrun * rs + sum;

      // ---- rescale O (per-reg row factors via shfl) ----
#pragma unroll
      for (int r = 0; r < 16; ++r) {
        float rsb = __shfl(rs, (r & 3) + 8 * (r >> 2) + hi4);
        oacc0[r] *= rsb;
        oacc1[r] *= rsb;
      }

      // ---- P -> bf16 A-frags (proven primitives) ----
      bf16x8 paf0, paf1, paf2, paf3;
      pfrag(st0, hi, paf0, paf1);
      pfrag(st1, hi, paf2, paf3);

      // ---- PV: O[q][d] += P[q][ks*16..] * V[ks*16..][d] ----
#pragma unroll
      for (int ks = 0; ks < 4; ++ks) {
        bf16x8 pa = (ks == 0) ? paf0 : (ks == 1) ? paf1 : (ks == 2) ? paf2 : paf3;
        int d0 = l31;
        bf16x8 vf0 = *(const bf16x8*)(Vt + d0 * 64 + (((ks * 2 + hi) ^ ((d0 >> 2) & 7)) << 3));
        int d1 = 32 + l31;
        bf16x8 vf1 = *(const bf16x8*)(Vt + d1 * 64 + (((ks * 2 + hi) ^ ((d1 >> 2) & 7)) << 3));
        oacc0 = __builtin_amdgcn_mfma_f32_32x32x16_bf16(pa, vf0, oacc0, 0, 0, 0);
        oacc1 = __builtin_amdgcn_mfma_f32_32x32x16_bf16(pa, vf1, oacc1, 0, 0, 0);
      }
    }
    __syncthreads();   // everyone done with Ks[cur]/Vt; prefetch drained here
  }

  // ---- epilogue: divide by row-sum, write ctx[B*S][D] bf16 ----
  const int b = bh >> 4, h = bh & (NH - 1);
#pragma unroll
  for (int r = 0; r < 16; ++r) {
    float lr = __shfl(lrun, (r & 3) + 8 * (r >> 2) + hi4);
    float inv = 1.0f / lr;
    int srow = Qw + (r & 3) + 8 * (r >> 2) + hi4;
    size_t rowbase = ((size_t)b * S_LEN + srow) * D_DIM + h * HD;
    ctx[rowbase + l31] = f2bf(oacc0[r] * inv);
    ctx[rowbase + 32 + l31] = f2bf(oacc1[r] * inv);
  }
}

// ---------------- host launcher ----------------
extern "C" void kernel_launch(void* const* d_in, const int* in_sizes, int n_in,
                              void* d_out, int out_size, void* d_ws, size_t ws_size,
                              hipStream_t stream) {
  const float* x  = (const float*)d_in[0];
  const float* Wq = (const float*)d_in[1];
  const float* bq = (const float*)d_in[2];
  const float* Wk = (const float*)d_in[3];
  const float* bk = (const float*)d_in[4];
  const float* Wv = (const float*)d_in[5];
  const float* bv = (const float*)d_in[6];
  const float* Wo = (const float*)d_in[7];
  const float* bo = (const float*)d_in[8];

  char* ws = (char*)d_ws;
  const size_t MB = 1024 * 1024;
  u16* xb   = (u16*)(ws + 0);
  u16* Wqb  = (u16*)(ws + 16 * MB);
  u16* Wkb  = (u16*)(ws + 18 * MB);
  u16* Wvb  = (u16*)(ws + 20 * MB);
  u16* Wob  = (u16*)(ws + 22 * MB);
  u16* Qb   = (u16*)(ws + 24 * MB);
  u16* Kb   = (u16*)(ws + 40 * MB);
  u16* Vb   = (u16*)(ws + 56 * MB);
  u16* ctxb = xb;

  cvt_bf16_kernel<<<(M_ROWS * D_DIM / 4 + 255) / 256, 256, 0, stream>>>(x, xb, M_ROWS * D_DIM / 4);
  cvt_bf16_kernel<<<(D_DIM * D_DIM / 4 + 255) / 256, 256, 0, stream>>>(Wq, Wqb, D_DIM * D_DIM / 4);
  cvt_bf16_kernel<<<(D_DIM * D_DIM / 4 + 255) / 256, 256, 0, stream>>>(Wk, Wkb, D_DIM * D_DIM / 4);
  cvt_bf16_kernel<<<(D_DIM * D_DIM / 4 + 255) / 256, 256, 0, stream>>>(Wv, Wvb, D_DIM * D_DIM / 4);
  cvt_bf16_kernel<<<(D_DIM * D_DIM / 4 + 255) / 256, 256, 0, stream>>>(Wo, Wob, D_DIM * D_DIM / 4);

  dim3 gg(D_DIM / 128, M_ROWS / 128);
  gemm_bt_kernel<0><<<gg, 256, 0, stream>>>(xb, Wqb, bq, Qb, M_ROWS, D_DIM, D_DIM, 0.125f);
  gemm_bt_kernel<0><<<gg, 256, 0, stream>>>(xb, Wkb, bk, Kb, M_ROWS, D_DIM, D_DIM, 1.0f);
  gemm_bt_kernel<0><<<gg, 256, 0, stream>>>(xb, Wvb, bv, Vb, M_ROWS, D_DIM, D_DIM, 1.0f);

  attn_kernel<<<dim3(S_LEN / 128, BATCH * NH), 256, 0, stream>>>(Qb, Kb, Vb, ctxb);

  gemm_bt_kernel<1><<<gg, 256, 0, stream>>>(ctxb, Wob, bo, (float*)d_out, M_ROWS, D_DIM, D_DIM, 1.0f);
}

// Round 7
// 223.761 us; speedup vs baseline: 1.7654x; 1.3255x over previous
//
#include <hip/hip_runtime.h>
#include <stdint.h>

// ---- problem constants ----
#define BATCH 4
#define S_LEN 2048
#define D_DIM 1024
#define NH 16
#define HD 64
#define M_ROWS (BATCH * S_LEN)  // 8192
#define NQB (S_LEN / 128)       // 16 q-blocks

using u16 = unsigned short;
typedef __attribute__((ext_vector_type(8))) __bf16 bf16x8;
typedef __attribute__((ext_vector_type(4))) float f32x4;
typedef __attribute__((ext_vector_type(16))) float f32x16;
typedef __attribute__((ext_vector_type(8))) unsigned short u16x8;

__device__ __forceinline__ u16 f2bf(float f) {
  unsigned u = __builtin_bit_cast(unsigned, f);
  u += 0x7fffu + ((u >> 16) & 1u);  // RNE
  return (u16)(u >> 16);
}
__device__ __forceinline__ unsigned pk2(float lo, float hi) {
  return (unsigned)f2bf(lo) | ((unsigned)f2bf(hi) << 16);
}

// ---------------- fp32 -> bf16 conversion ----------------
__global__ void cvt_bf16_kernel(const float* __restrict__ in, u16* __restrict__ out, int n4) {
  int i = blockIdx.x * blockDim.x + threadIdx.x;
  if (i < n4) {
    float4 v = ((const float4*)in)[i];
    ushort4 o;
    o.x = f2bf(v.x); o.y = f2bf(v.y); o.z = f2bf(v.z); o.w = f2bf(v.w);
    ((ushort4*)out)[i] = o;
  }
}

// ---------------- bf16 GEMM: C = (A*Bt^T + bias) * scale ----------------
template<int MODE>  // 0: bf16 out in [B,H,S,HD]; 1: fp32 out [M,N]
__global__ __launch_bounds__(256)
void gemm_bt_kernel(const u16* __restrict__ A, const u16* __restrict__ Bt,
                    const float* __restrict__ bias, void* __restrict__ Cout,
                    int M, int N, int K, float scale) {
  __shared__ __align__(16) u16 As[128 * 64];
  __shared__ __align__(16) u16 Bs[128 * 64];
  const int tid = threadIdx.x;
  const int w = tid >> 6;
  const int lane = tid & 63;
  const int l15 = lane & 15, l4 = lane >> 4;
  const int m0 = blockIdx.y * 128, n0 = blockIdx.x * 128;
  const int wr = (w >> 1) * 64, wc = (w & 1) * 64;

  f32x4 acc[4][4] = {};

  for (int k0 = 0; k0 < K; k0 += 64) {
    __syncthreads();
#pragma unroll
    for (int i = 0; i < 4; ++i) {
      int chunk = w * 4 + i;
      int o = chunk * 1024 + lane * 16;
      int row = o >> 7;
      int g = (o >> 4) & 7;
      int gs = g ^ (row & 7);
      const u16* gA = A + (size_t)(m0 + row) * K + k0 + gs * 8;
      const u16* gB = Bt + (size_t)(n0 + row) * K + k0 + gs * 8;
      __builtin_amdgcn_global_load_lds((const __attribute__((address_space(1))) void*)gA,
                                       (__attribute__((address_space(3))) void*)(As + chunk * 512),
                                       16, 0, 0);
      __builtin_amdgcn_global_load_lds((const __attribute__((address_space(1))) void*)gB,
                                       (__attribute__((address_space(3))) void*)(Bs + chunk * 512),
                                       16, 0, 0);
    }
    __syncthreads();

    bf16x8 a[4][2];
#pragma unroll
    for (int mb = 0; mb < 4; ++mb) {
#pragma unroll
      for (int ks = 0; ks < 2; ++ks) {
        int row = wr + mb * 16 + l15;
        int gsw = (ks * 4 + l4) ^ (row & 7);
        a[mb][ks] = *(const bf16x8*)(As + row * 64 + gsw * 8);
      }
    }
#pragma unroll
    for (int nb = 0; nb < 4; ++nb) {
      int row = wc + nb * 16 + l15;
      int g0 = (0 + l4) ^ (row & 7);
      int g1 = (4 + l4) ^ (row & 7);
      bf16x8 b0 = *(const bf16x8*)(Bs + row * 64 + g0 * 8);
      bf16x8 b1 = *(const bf16x8*)(Bs + row * 64 + g1 * 8);
#pragma unroll
      for (int mb = 0; mb < 4; ++mb) {
        acc[mb][nb] = __builtin_amdgcn_mfma_f32_16x16x32_bf16(a[mb][0], b0, acc[mb][nb], 0, 0, 0);
        acc[mb][nb] = __builtin_amdgcn_mfma_f32_16x16x32_bf16(a[mb][1], b1, acc[mb][nb], 0, 0, 0);
      }
    }
  }

#pragma unroll
  for (int mb = 0; mb < 4; ++mb) {
#pragma unroll
    for (int nb = 0; nb < 4; ++nb) {
#pragma unroll
      for (int r = 0; r < 4; ++r) {
        int m = m0 + wr + mb * 16 + l4 * 4 + r;
        int n = n0 + wc + nb * 16 + l15;
        float v = (acc[mb][nb][r] + bias[n]) * scale;
        if (MODE == 0) {
          int bb = m >> 11;
          int ss = m & (S_LEN - 1);
          int hh = n >> 6;
          int hd = n & (HD - 1);
          ((u16*)Cout)[(((size_t)bb * NH + hh) * S_LEN + ss) * HD + hd] = f2bf(v);
        } else {
          ((float*)Cout)[(size_t)m * N + n] = v;
        }
      }
    }
  }
}

// ---------------- causal flash attention, swapped QK^T, 32x32 MFMA ----------------
// Block pairs q-blocks {bid, NQB-1-bid} -> uniform 34 K-iterations per block.
// Per wave: 32 queries. S^T = mfma(K, Q): lane holds S[key(r,hi)][q=l31].
// Softmax in-register; exact defer-rescale (skip when no query's max grows).
__device__ __forceinline__ void stage_k(const u16* __restrict__ Kg, size_t base, int kt,
                                        u16* Kd, int w, int lane) {
#pragma unroll
  for (int i = 0; i < 2; ++i) {
    int ic = w * 2 + i;
    int c = ic * 64 + lane;                 // 16B chunk index, 0..511
    int row = c >> 3, g = c & 7, gs = g ^ (row & 7);
    __builtin_amdgcn_global_load_lds(
        (const __attribute__((address_space(1))) void*)(Kg + base + (size_t)(kt * 64 + row) * HD + gs * 8),
        (__attribute__((address_space(3))) void*)(Kd + ic * 512), 16, 0, 0);
  }
}

// build two A-frags (keys 0..15 and 16..31 of a 32-key half) from st
__device__ __forceinline__ void pfrag(const f32x16& st, int hi, bf16x8& fa, bf16x8& fb) {
  unsigned c0 = pk2(st[0], st[1]),   c1 = pk2(st[2], st[3]);
  unsigned c2 = pk2(st[4], st[5]),   c3 = pk2(st[6], st[7]);
  unsigned c4 = pk2(st[8], st[9]),   c5 = pk2(st[10], st[11]);
  unsigned c6 = pk2(st[12], st[13]), c7 = pk2(st[14], st[15]);
  unsigned p0 = __shfl_xor(c0, 32), p1 = __shfl_xor(c1, 32);
  unsigned p2 = __shfl_xor(c2, 32), p3 = __shfl_xor(c3, 32);
  unsigned p4 = __shfl_xor(c4, 32), p5 = __shfl_xor(c5, 32);
  unsigned p6 = __shfl_xor(c6, 32), p7 = __shfl_xor(c7, 32);
  union { unsigned u[4]; bf16x8 v; } a, b;
  a.u[0] = hi ? p2 : c0; a.u[1] = hi ? p3 : c1;
  a.u[2] = hi ? c2 : p0; a.u[3] = hi ? c3 : p1;
  b.u[0] = hi ? p6 : c4; b.u[1] = hi ? p7 : c5;
  b.u[2] = hi ? c6 : p4; b.u[3] = hi ? c7 : p5;
  fa = a.v; fb = b.v;
}

__global__ __launch_bounds__(256)
void attn_kernel(const u16* __restrict__ Q, const u16* __restrict__ Kg,
                 const u16* __restrict__ Vg, u16* __restrict__ ctx) {
  __shared__ __align__(16) u16 Ks[2][64 * 64];   // K double buffer
  __shared__ __align__(16) u16 Vt[64 * 64];      // V^T [d][key], granule-XOR swizzled

  const int tid = threadIdx.x;
  const int w = tid >> 6, lane = tid & 63;
  const int l31 = lane & 31, hi = lane >> 5;
  const int hi4 = hi * 4, hi8 = hi * 8;
  const int bh = blockIdx.y;
  const size_t base = (size_t)bh * S_LEN * HD;
  const int b = bh >> 4, h = bh & (NH - 1);

  const int vrow = tid >> 2;          // key row this thread transposes
  const int vc0 = (tid & 3) * 16;     // d-range start

#pragma unroll 1
  for (int seg = 0; seg < 2; ++seg) {
    const int qb = seg ? (NQB - 1 - blockIdx.x) : blockIdx.x;
    const int Qw = qb * 128 + w * 32;
    const int q_g = Qw + l31;

    // Q fragments (pre-scaled by 1/8): qf[step] = Q[q_g][step*16 + hi8 .. +8]
    bf16x8 qf[4];
#pragma unroll
    for (int step = 0; step < 4; ++step)
      qf[step] = *(const bf16x8*)(Q + base + (size_t)q_g * HD + step * 16 + hi8);

    f32x16 oacc0 = {}, oacc1 = {};   // O[q][d]: col=d=l31 (+32), row q=(r&3)+8*(r>>2)+hi4
    float mrun = -1e30f, lrun = 0.f;

    const int nkt = 2 * qb + 2;

    stage_k(Kg, base, 0, Ks[0], w, lane);
    u16x8 vv0, vv1;
    {
      const u16* gv = Vg + base + (size_t)vrow * HD + vc0;
      vv0 = *(const u16x8*)gv;
      vv1 = *(const u16x8*)(gv + 8);
    }

    for (int kt = 0; kt < nkt; ++kt) {
      const int cur = kt & 1;
      const bool more = (kt + 1 < nkt);

      // V(kt) regs -> Vt (transpose), granule XOR by (d>>2)&7
#pragma unroll
      for (int j = 0; j < 8; ++j) {
        int d0 = vc0 + j;
        Vt[d0 * 64 + (((vrow >> 3) ^ ((d0 >> 2) & 7)) << 3) + (vrow & 7)] = vv0[j];
        int d1 = vc0 + 8 + j;
        Vt[d1 * 64 + (((vrow >> 3) ^ ((d1 >> 2) & 7)) << 3) + (vrow & 7)] = vv1[j];
      }
      __syncthreads();   // Vt + Ks[cur] ready

      if (more) {
        stage_k(Kg, base, kt + 1, Ks[cur ^ 1], w, lane);
        const u16* gv = Vg + base + (size_t)((kt + 1) * 64 + vrow) * HD + vc0;
        vv0 = *(const u16x8*)gv;
        vv1 = *(const u16x8*)(gv + 8);
      }

      const u16* Kb = &Ks[cur][0];

      if (kt * 64 <= Qw + 31) {
        // ---- swapped QK^T: st[key][q] ----
        f32x16 st0 = {}, st1 = {};
#pragma unroll
        for (int step = 0; step < 4; ++step) {
          int r0 = l31, r1 = 32 + l31;
          bf16x8 kf0 = *(const bf16x8*)(Kb + r0 * 64 + (((step * 2 + hi) ^ (r0 & 7)) << 3));
          bf16x8 kf1 = *(const bf16x8*)(Kb + r1 * 64 + (((step * 2 + hi) ^ (r1 & 7)) << 3));
          st0 = __builtin_amdgcn_mfma_f32_32x32x16_bf16(kf0, qf[step], st0, 0, 0, 0);
          st1 = __builtin_amdgcn_mfma_f32_32x32x16_bf16(kf1, qf[step], st1, 0, 0, 0);
        }

        // ---- causal mask ----
        if (kt * 64 + 63 > Qw) {
#pragma unroll
          for (int r = 0; r < 16; ++r) {
            int key0 = kt * 64 + hi4 + (r & 3) + 8 * (r >> 2);
            if (key0 > q_g) st0[r] = -1e30f;
            if (key0 + 32 > q_g) st1[r] = -1e30f;
          }
        }

        // ---- in-register softmax (row = query = l31; partner lane l31+32) ----
        float tm = -1e30f;
#pragma unroll
        for (int r = 0; r < 16; ++r) { tm = fmaxf(tm, st0[r]); tm = fmaxf(tm, st1[r]); }
        tm = fmaxf(tm, __shfl_xor(tm, 32));

        // exact defer-rescale: only rescale when some query's max grew
        if (__any(tm > mrun)) {
          float mnew = fmaxf(mrun, tm);
          float rs = __expf(mrun - mnew);
          mrun = mnew;
          lrun *= rs;
#pragma unroll
          for (int r = 0; r < 16; ++r) {
            float rsb = __shfl(rs, (r & 3) + 8 * (r >> 2) + hi4);
            oacc0[r] *= rsb;
            oacc1[r] *= rsb;
          }
        }

        float sum = 0.f;
#pragma unroll
        for (int r = 0; r < 16; ++r) {
          st0[r] = __expf(st0[r] - mrun); sum += st0[r];
          st1[r] = __expf(st1[r] - mrun); sum += st1[r];
        }
        sum += __shfl_xor(sum, 32);
        lrun += sum;

        // ---- P -> bf16 A-frags ----
        bf16x8 paf0, paf1, paf2, paf3;
        pfrag(st0, hi, paf0, paf1);
        pfrag(st1, hi, paf2, paf3);

        // ---- PV: O[q][d] += P[q][ks*16..] * V[ks*16..][d] ----
#pragma unroll
        for (int ks = 0; ks < 4; ++ks) {
          bf16x8 pa = (ks == 0) ? paf0 : (ks == 1) ? paf1 : (ks == 2) ? paf2 : paf3;
          int d0 = l31;
          bf16x8 vf0 = *(const bf16x8*)(Vt + d0 * 64 + (((ks * 2 + hi) ^ ((d0 >> 2) & 7)) << 3));
          int d1 = 32 + l31;
          bf16x8 vf1 = *(const bf16x8*)(Vt + d1 * 64 + (((ks * 2 + hi) ^ ((d1 >> 2) & 7)) << 3));
          oacc0 = __builtin_amdgcn_mfma_f32_32x32x16_bf16(pa, vf0, oacc0, 0, 0, 0);
          oacc1 = __builtin_amdgcn_mfma_f32_32x32x16_bf16(pa, vf1, oacc1, 0, 0, 0);
        }
      }
      __syncthreads();   // everyone done with Ks[cur]/Vt; prefetch drained here
    }

    // ---- epilogue: divide by row-sum, write ctx[B*S][D] bf16 ----
#pragma unroll
    for (int r = 0; r < 16; ++r) {
      float lr = __shfl(lrun, (r & 3) + 8 * (r >> 2) + hi4);
      float inv = 1.0f / lr;
      int srow = Qw + (r & 3) + 8 * (r >> 2) + hi4;
      size_t rowbase = ((size_t)b * S_LEN + srow) * D_DIM + h * HD;
      ctx[rowbase + l31] = f2bf(oacc0[r] * inv);
      ctx[rowbase + 32 + l31] = f2bf(oacc1[r] * inv);
    }
  }
}

// ---------------- host launcher ----------------
extern "C" void kernel_launch(void* const* d_in, const int* in_sizes, int n_in,
                              void* d_out, int out_size, void* d_ws, size_t ws_size,
                              hipStream_t stream) {
  const float* x  = (const float*)d_in[0];
  const float* Wq = (const float*)d_in[1];
  const float* bq = (const float*)d_in[2];
  const float* Wk = (const float*)d_in[3];
  const float* bk = (const float*)d_in[4];
  const float* Wv = (const float*)d_in[5];
  const float* bv = (const float*)d_in[6];
  const float* Wo = (const float*)d_in[7];
  const float* bo = (const float*)d_in[8];

  char* ws = (char*)d_ws;
  const size_t MB = 1024 * 1024;
  u16* xb   = (u16*)(ws + 0);
  u16* Wqb  = (u16*)(ws + 16 * MB);
  u16* Wkb  = (u16*)(ws + 18 * MB);
  u16* Wvb  = (u16*)(ws + 20 * MB);
  u16* Wob  = (u16*)(ws + 22 * MB);
  u16* Qb   = (u16*)(ws + 24 * MB);
  u16* Kb   = (u16*)(ws + 40 * MB);
  u16* Vb   = (u16*)(ws + 56 * MB);
  u16* ctxb = xb;

  cvt_bf16_kernel<<<(M_ROWS * D_DIM / 4 + 255) / 256, 256, 0, stream>>>(x, xb, M_ROWS * D_DIM / 4);
  cvt_bf16_kernel<<<(D_DIM * D_DIM / 4 + 255) / 256, 256, 0, stream>>>(Wq, Wqb, D_DIM * D_DIM / 4);
  cvt_bf16_kernel<<<(D_DIM * D_DIM / 4 + 255) / 256, 256, 0, stream>>>(Wk, Wkb, D_DIM * D_DIM / 4);
  cvt_bf16_kernel<<<(D_DIM * D_DIM / 4 + 255) / 256, 256, 0, stream>>>(Wv, Wvb, D_DIM * D_DIM / 4);
  cvt_bf16_kernel<<<(D_DIM * D_DIM / 4 + 255) / 256, 256, 0, stream>>>(Wo, Wob, D_DIM * D_DIM / 4);

  dim3 gg(D_DIM / 128, M_ROWS / 128);
  gemm_bt_kernel<0><<<gg, 256, 0, stream>>>(xb, Wqb, bq, Qb, M_ROWS, D_DIM, D_DIM, 0.125f);
  gemm_bt_kernel<0><<<gg, 256, 0, stream>>>(xb, Wkb, bk, Kb, M_ROWS, D_DIM, D_DIM, 1.0f);
  gemm_bt_kernel<0><<<gg, 256, 0, stream>>>(xb, Wvb, bv, Vb, M_ROWS, D_DIM, D_DIM, 1.0f);

  attn_kernel<<<dim3(NQB / 2, BATCH * NH), 256, 0, stream>>>(Qb, Kb, Vb, ctxb);

  gemm_bt_kernel<1><<<gg, 256, 0, stream>>>(ctxb, Wob, bo, (float*)d_out, M_ROWS, D_DIM, D_DIM, 1.0f);
}

// Round 11
// 200.903 us; speedup vs baseline: 1.9663x; 1.1138x over previous
//
#include <hip/hip_runtime.h>
#include <stdint.h>

// ---- problem constants ----
#define BATCH 4
#define S_LEN 2048
#define D_DIM 1024
#define NH 16
#define HD 64
#define M_ROWS (BATCH * S_LEN)  // 8192
#define NQB (S_LEN / 128)       // 16 q-blocks
#define QSCALE 0.18033688011f   // 0.125 * log2(e): exp2-domain scores

using u16 = unsigned short;
typedef __attribute__((ext_vector_type(8))) __bf16 bf16x8;
typedef __attribute__((ext_vector_type(4))) float f32x4;
typedef __attribute__((ext_vector_type(16))) float f32x16;
typedef __attribute__((ext_vector_type(8))) unsigned short u16x8;

__device__ __forceinline__ float exp2fast(float x) { return __builtin_amdgcn_exp2f(x); }

__device__ __forceinline__ u16 f2bf(float f) {
  unsigned u = __builtin_bit_cast(unsigned, f);
  u += 0x7fffu + ((u >> 16) & 1u);  // RNE
  return (u16)(u >> 16);
}
// proven pack (r7): two f32 -> two bf16 in one u32
__device__ __forceinline__ unsigned pk2(float lo, float hi) {
  return (unsigned)f2bf(lo) | ((unsigned)f2bf(hi) << 16);
}

// ---------------- fp32 -> bf16 conversions ----------------
__global__ void cvt_bf16_kernel(const float* __restrict__ in, u16* __restrict__ out, int n4) {
  int i = blockIdx.x * blockDim.x + threadIdx.x;
  if (i < n4) {
    float4 v = ((const float4*)in)[i];
    ushort4 o;
    o.x = f2bf(v.x); o.y = f2bf(v.y); o.z = f2bf(v.z); o.w = f2bf(v.w);
    ((ushort4*)out)[i] = o;
  }
}

// all 4 weight matrices in one launch: y selects source; dst contiguous
__global__ void cvt_w_kernel(const float* __restrict__ W0, const float* __restrict__ W1,
                             const float* __restrict__ W2, const float* __restrict__ W3,
                             u16* __restrict__ out) {
  int y = blockIdx.y;
  const float* src = (y == 0) ? W0 : (y == 1) ? W1 : (y == 2) ? W2 : W3;
  u16* dst = out + (size_t)y * D_DIM * D_DIM;
  int i = blockIdx.x * blockDim.x + threadIdx.x;
  float4 v = ((const float4*)src)[i];
  ushort4 o;
  o.x = f2bf(v.x); o.y = f2bf(v.y); o.z = f2bf(v.z); o.w = f2bf(v.w);
  ((ushort4*)dst)[i] = o;
}

// ---------------- GEMM tile staging: 128 rows x 64 cols bf16 = 16KB = 1024 chunks ----
// ic = w*4+i in 0..15, c in 0..1023, row = c>>3 in 0..127  (== r7's proven inline form)
__device__ __forceinline__ void stage_tile(const u16* __restrict__ src, int srcK,
                                           u16* dst, int w, int lane) {
#pragma unroll
  for (int i = 0; i < 4; ++i) {
    int ic = w * 4 + i;
    int c = ic * 64 + lane;                 // 16B chunk index, 0..1023
    int row = c >> 3, g = c & 7, gs = g ^ (row & 7);
    __builtin_amdgcn_global_load_lds(
        (const __attribute__((address_space(1))) void*)(src + (size_t)row * srcK + gs * 8),
        (__attribute__((address_space(3))) void*)(dst + ic * 512), 16, 0, 0);
  }
}

// ---------------- fused QKV GEMM: [8192x1024] x [3072x1024]^T ----------------
// Bt rows 0-1023 = Wq, 1024-2047 = Wk, 2048-3071 = Wv. Q gets QSCALE.
__global__ __launch_bounds__(256)
void gemm_qkv_kernel(const u16* __restrict__ A, const u16* __restrict__ Bt,
                     const float* __restrict__ bq, const float* __restrict__ bk,
                     const float* __restrict__ bv,
                     u16* __restrict__ Qo, u16* __restrict__ Ko, u16* __restrict__ Vo) {
  __shared__ __align__(16) u16 As[128 * 64];
  __shared__ __align__(16) u16 Bs[128 * 64];
  const int tid = threadIdx.x;
  const int w = tid >> 6;
  const int lane = tid & 63;
  const int l15 = lane & 15, l4 = lane >> 4;
  const int m0 = blockIdx.y * 128, n0 = blockIdx.x * 128;
  const int wr = (w >> 1) * 64, wc = (w & 1) * 64;
  const int K = D_DIM;

  f32x4 acc[4][4] = {};

  for (int k0 = 0; k0 < K; k0 += 64) {
    __syncthreads();
    stage_tile(A + (size_t)m0 * K + k0, K, As, w, lane);
    stage_tile(Bt + (size_t)n0 * K + k0, K, Bs, w, lane);
    __syncthreads();

    bf16x8 a[4][2];
#pragma unroll
    for (int mb = 0; mb < 4; ++mb) {
#pragma unroll
      for (int ks = 0; ks < 2; ++ks) {
        int row = wr + mb * 16 + l15;
        int gsw = (ks * 4 + l4) ^ (row & 7);
        a[mb][ks] = *(const bf16x8*)(As + row * 64 + gsw * 8);
      }
    }
#pragma unroll
    for (int nb = 0; nb < 4; ++nb) {
      int row = wc + nb * 16 + l15;
      int g0 = (0 + l4) ^ (row & 7);
      int g1 = (4 + l4) ^ (row & 7);
      bf16x8 b0 = *(const bf16x8*)(Bs + row * 64 + g0 * 8);
      bf16x8 b1 = *(const bf16x8*)(Bs + row * 64 + g1 * 8);
#pragma unroll
      for (int mb = 0; mb < 4; ++mb) {
        acc[mb][nb] = __builtin_amdgcn_mfma_f32_16x16x32_bf16(a[mb][0], b0, acc[mb][nb], 0, 0, 0);
        acc[mb][nb] = __builtin_amdgcn_mfma_f32_16x16x32_bf16(a[mb][1], b1, acc[mb][nb], 0, 0, 0);
      }
    }
  }

  // which segment (Q/K/V) is block-uniform: n0 is a multiple of 128, 128 | 1024
  const int which = n0 >> 10;
  const float* bias = (which == 0) ? bq : (which == 1) ? bk : bv;
  u16* dst = (which == 0) ? Qo : (which == 1) ? Ko : Vo;
  const float scale = (which == 0) ? QSCALE : 1.0f;

#pragma unroll
  for (int mb = 0; mb < 4; ++mb) {
#pragma unroll
    for (int nb = 0; nb < 4; ++nb) {
#pragma unroll
      for (int r = 0; r < 4; ++r) {
        int m = m0 + wr + mb * 16 + l4 * 4 + r;
        int n = n0 + wc + nb * 16 + l15;
        int col = n & 1023;
        float v = (acc[mb][nb][r] + bias[col]) * scale;
        int bb = m >> 11;
        int ss = m & (S_LEN - 1);
        int hh = col >> 6;
        int hd = col & (HD - 1);
        dst[(((size_t)bb * NH + hh) * S_LEN + ss) * HD + hd] = f2bf(v);
      }
    }
  }
}

// ---------------- output projection GEMM (fp32 out) ----------------
__global__ __launch_bounds__(256)
void gemm_out_kernel(const u16* __restrict__ A, const u16* __restrict__ Bt,
                     const float* __restrict__ bias, float* __restrict__ Cout) {
  __shared__ __align__(16) u16 As[128 * 64];
  __shared__ __align__(16) u16 Bs[128 * 64];
  const int tid = threadIdx.x;
  const int w = tid >> 6;
  const int lane = tid & 63;
  const int l15 = lane & 15, l4 = lane >> 4;
  const int m0 = blockIdx.y * 128, n0 = blockIdx.x * 128;
  const int wr = (w >> 1) * 64, wc = (w & 1) * 64;
  const int K = D_DIM, N = D_DIM;

  f32x4 acc[4][4] = {};

  for (int k0 = 0; k0 < K; k0 += 64) {
    __syncthreads();
    stage_tile(A + (size_t)m0 * K + k0, K, As, w, lane);
    stage_tile(Bt + (size_t)n0 * K + k0, K, Bs, w, lane);
    __syncthreads();

    bf16x8 a[4][2];
#pragma unroll
    for (int mb = 0; mb < 4; ++mb) {
#pragma unroll
      for (int ks = 0; ks < 2; ++ks) {
        int row = wr + mb * 16 + l15;
        int gsw = (ks * 4 + l4) ^ (row & 7);
        a[mb][ks] = *(const bf16x8*)(As + row * 64 + gsw * 8);
      }
    }
#pragma unroll
    for (int nb = 0; nb < 4; ++nb) {
      int row = wc + nb * 16 + l15;
      int g0 = (0 + l4) ^ (row & 7);
      int g1 = (4 + l4) ^ (row & 7);
      bf16x8 b0 = *(const bf16x8*)(Bs + row * 64 + g0 * 8);
      bf16x8 b1 = *(const bf16x8*)(Bs + row * 64 + g1 * 8);
#pragma unroll
      for (int mb = 0; mb < 4; ++mb) {
        acc[mb][nb] = __builtin_amdgcn_mfma_f32_16x16x32_bf16(a[mb][0], b0, acc[mb][nb], 0, 0, 0);
        acc[mb][nb] = __builtin_amdgcn_mfma_f32_16x16x32_bf16(a[mb][1], b1, acc[mb][nb], 0, 0, 0);
      }
    }
  }

#pragma unroll
  for (int mb = 0; mb < 4; ++mb) {
#pragma unroll
    for (int nb = 0; nb < 4; ++nb) {
#pragma unroll
      for (int r = 0; r < 4; ++r) {
        int m = m0 + wr + mb * 16 + l4 * 4 + r;
        int n = n0 + wc + nb * 16 + l15;
        Cout[(size_t)m * N + n] = acc[mb][nb][r] + bias[n];
      }
    }
  }
}

// ---------------- causal flash attention, swapped QK^T, 32x32 MFMA ----------------
// Block pairs q-blocks {bid, NQB-1-bid}; log2-domain scores (Q pre-scaled).
// stage_k covers 64x64 tile = 8KB = 512 chunks (ic = w*2+i, correct for attn).
__device__ __forceinline__ void stage_k(const u16* __restrict__ Kg, size_t base, int kt,
                                        u16* Kd, int w, int lane) {
#pragma unroll
  for (int i = 0; i < 2; ++i) {
    int ic = w * 2 + i;
    int c = ic * 64 + lane;
    int row = c >> 3, g = c & 7, gs = g ^ (row & 7);
    __builtin_amdgcn_global_load_lds(
        (const __attribute__((address_space(1))) void*)(Kg + base + (size_t)(kt * 64 + row) * HD + gs * 8),
        (__attribute__((address_space(3))) void*)(Kd + ic * 512), 16, 0, 0);
  }
}

// build two A-frags (keys 0..15 and 16..31 of a 32-key half) from st
__device__ __forceinline__ void pfrag(const f32x16& st, int hi, bf16x8& fa, bf16x8& fb) {
  unsigned c0 = pk2(st[0], st[1]),   c1 = pk2(st[2], st[3]);
  unsigned c2 = pk2(st[4], st[5]),   c3 = pk2(st[6], st[7]);
  unsigned c4 = pk2(st[8], st[9]),   c5 = pk2(st[10], st[11]);
  unsigned c6 = pk2(st[12], st[13]), c7 = pk2(st[14], st[15]);
  unsigned p0 = __shfl_xor(c0, 32), p1 = __shfl_xor(c1, 32);
  unsigned p2 = __shfl_xor(c2, 32), p3 = __shfl_xor(c3, 32);
  unsigned p4 = __shfl_xor(c4, 32), p5 = __shfl_xor(c5, 32);
  unsigned p6 = __shfl_xor(c6, 32), p7 = __shfl_xor(c7, 32);
  union { unsigned u[4]; bf16x8 v; } a, b;
  a.u[0] = hi ? p2 : c0; a.u[1] = hi ? p3 : c1;
  a.u[2] = hi ? c2 : p0; a.u[3] = hi ? c3 : p1;
  b.u[0] = hi ? p6 : c4; b.u[1] = hi ? p7 : c5;
  b.u[2] = hi ? c6 : p4; b.u[3] = hi ? c7 : p5;
  fa = a.v; fb = b.v;
}

__global__ __launch_bounds__(256)
void attn_kernel(const u16* __restrict__ Q, const u16* __restrict__ Kg,
                 const u16* __restrict__ Vg, u16* __restrict__ ctx) {
  __shared__ __align__(16) u16 Ks[2][64 * 64];   // K double buffer
  __shared__ __align__(16) u16 Vt[64 * 64];      // V^T [d][key], granule-XOR swizzled

  const int tid = threadIdx.x;
  const int w = tid >> 6, lane = tid & 63;
  const int l31 = lane & 31, hi = lane >> 5;
  const int hi4 = hi * 4, hi8 = hi * 8;
  const int bh = blockIdx.y;
  const size_t base = (size_t)bh * S_LEN * HD;
  const int b = bh >> 4, h = bh & (NH - 1);

  // V staging: thread owns key=tid&63, d-range (tid>>6)*16 .. +16.
  const int vkey = tid & 63;
  const int vd0 = (tid >> 6) * 16;

#pragma unroll 1
  for (int seg = 0; seg < 2; ++seg) {
    const int qb = seg ? (NQB - 1 - blockIdx.x) : blockIdx.x;
    const int Qw = qb * 128 + w * 32;
    const int q_g = Qw + l31;

    bf16x8 qf[4];
#pragma unroll
    for (int step = 0; step < 4; ++step)
      qf[step] = *(const bf16x8*)(Q + base + (size_t)q_g * HD + step * 16 + hi8);

    f32x16 oacc0 = {}, oacc1 = {};
    float mrun = -1e30f, lrun = 0.f;

    const int nkt = 2 * qb + 2;

    stage_k(Kg, base, 0, Ks[0], w, lane);
    u16x8 vv0, vv1;
    {
      const u16* gv = Vg + base + (size_t)vkey * HD + vd0;
      vv0 = *(const u16x8*)gv;
      vv1 = *(const u16x8*)(gv + 8);
    }

    for (int kt = 0; kt < nkt; ++kt) {
      const int cur = kt & 1;
      const bool more = (kt + 1 < nkt);

      // V(kt) regs -> Vt (transpose), granule XOR by (d>>2)&7
#pragma unroll
      for (int j = 0; j < 8; ++j) {
        int d0 = vd0 + j;
        Vt[d0 * 64 + (((vkey >> 3) ^ ((d0 >> 2) & 7)) << 3) + (vkey & 7)] = vv0[j];
        int d1 = vd0 + 8 + j;
        Vt[d1 * 64 + (((vkey >> 3) ^ ((d1 >> 2) & 7)) << 3) + (vkey & 7)] = vv1[j];
      }
      __syncthreads();   // Vt + Ks[cur] ready

      if (more) {
        stage_k(Kg, base, kt + 1, Ks[cur ^ 1], w, lane);
        const u16* gv = Vg + base + (size_t)((kt + 1) * 64 + vkey) * HD + vd0;
        vv0 = *(const u16x8*)gv;
        vv1 = *(const u16x8*)(gv + 8);
      }

      const u16* Kb = &Ks[cur][0];

      if (kt * 64 <= Qw + 31) {
        // ---- swapped QK^T: st[key][q] (log2-domain) ----
        f32x16 st0 = {}, st1 = {};
#pragma unroll
        for (int step = 0; step < 4; ++step) {
          int r0 = l31, r1 = 32 + l31;
          bf16x8 kf0 = *(const bf16x8*)(Kb + r0 * 64 + (((step * 2 + hi) ^ (r0 & 7)) << 3));
          bf16x8 kf1 = *(const bf16x8*)(Kb + r1 * 64 + (((step * 2 + hi) ^ (r1 & 7)) << 3));
          st0 = __builtin_amdgcn_mfma_f32_32x32x16_bf16(kf0, qf[step], st0, 0, 0, 0);
          st1 = __builtin_amdgcn_mfma_f32_32x32x16_bf16(kf1, qf[step], st1, 0, 0, 0);
        }

        // ---- causal mask ----
        if (kt * 64 + 63 > Qw) {
#pragma unroll
          for (int r = 0; r < 16; ++r) {
            int key0 = kt * 64 + hi4 + (r & 3) + 8 * (r >> 2);
            if (key0 > q_g) st0[r] = -1e30f;
            if (key0 + 32 > q_g) st1[r] = -1e30f;
          }
        }

        // ---- in-register softmax ----
        float tm = -1e30f;
#pragma unroll
        for (int r = 0; r < 16; ++r) { tm = fmaxf(tm, st0[r]); tm = fmaxf(tm, st1[r]); }
        tm = fmaxf(tm, __shfl_xor(tm, 32));

        if (__any(tm > mrun)) {          // exact defer-rescale
          float mnew = fmaxf(mrun, tm);
          float rs = exp2fast(mrun - mnew);
          mrun = mnew;
          lrun *= rs;
#pragma unroll
          for (int r = 0; r < 16; ++r) {
            float rsb = __shfl(rs, (r & 3) + 8 * (r >> 2) + hi4);
            oacc0[r] *= rsb;
            oacc1[r] *= rsb;
          }
        }

        float sum = 0.f;
#pragma unroll
        for (int r = 0; r < 16; ++r) {
          st0[r] = exp2fast(st0[r] - mrun); sum += st0[r];
          st1[r] = exp2fast(st1[r] - mrun); sum += st1[r];
        }
        sum += __shfl_xor(sum, 32);
        lrun += sum;

        // ---- P -> bf16 A-frags ----
        bf16x8 paf0, paf1, paf2, paf3;
        pfrag(st0, hi, paf0, paf1);
        pfrag(st1, hi, paf2, paf3);

        // ---- PV ----
#pragma unroll
        for (int ks = 0; ks < 4; ++ks) {
          bf16x8 pa = (ks == 0) ? paf0 : (ks == 1) ? paf1 : (ks == 2) ? paf2 : paf3;
          int d0 = l31;
          bf16x8 vf0 = *(const bf16x8*)(Vt + d0 * 64 + (((ks * 2 + hi) ^ ((d0 >> 2) & 7)) << 3));
          int d1 = 32 + l31;
          bf16x8 vf1 = *(const bf16x8*)(Vt + d1 * 64 + (((ks * 2 + hi) ^ ((d1 >> 2) & 7)) << 3));
          oacc0 = __builtin_amdgcn_mfma_f32_32x32x16_bf16(pa, vf0, oacc0, 0, 0, 0);
          oacc1 = __builtin_amdgcn_mfma_f32_32x32x16_bf16(pa, vf1, oacc1, 0, 0, 0);
        }
      }
      __syncthreads();
    }

    // ---- epilogue ----
#pragma unroll
    for (int r = 0; r < 16; ++r) {
      float lr = __shfl(lrun, (r & 3) + 8 * (r >> 2) + hi4);
      float inv = 1.0f / lr;
      int srow = Qw + (r & 3) + 8 * (r >> 2) + hi4;
      size_t rowbase = ((size_t)b * S_LEN + srow) * D_DIM + h * HD;
      ctx[rowbase + l31] = f2bf(oacc0[r] * inv);
      ctx[rowbase + 32 + l31] = f2bf(oacc1[r] * inv);
    }
  }
}

// ---------------- host launcher ----------------
extern "C" void kernel_launch(void* const* d_in, const int* in_sizes, int n_in,
                              void* d_out, int out_size, void* d_ws, size_t ws_size,
                              hipStream_t stream) {
  const float* x  = (const float*)d_in[0];
  const float* Wq = (const float*)d_in[1];
  const float* bq = (const float*)d_in[2];
  const float* Wk = (const float*)d_in[3];
  const float* bk = (const float*)d_in[4];
  const float* Wv = (const float*)d_in[5];
  const float* bv = (const float*)d_in[6];
  const float* Wo = (const float*)d_in[7];
  const float* bo = (const float*)d_in[8];

  char* ws = (char*)d_ws;
  const size_t MB = 1024 * 1024;
  u16* xb     = (u16*)(ws + 0);        // 16 MB [8192,1024] bf16
  u16* Wqkvb  = (u16*)(ws + 16 * MB);  // 6 MB  [3072,1024] bf16 (Wq|Wk|Wv rows)
  u16* Wob    = (u16*)(ws + 22 * MB);  // 2 MB
  u16* Qb     = (u16*)(ws + 24 * MB);  // 16 MB [B,H,S,HD]
  u16* Kb     = (u16*)(ws + 40 * MB);
  u16* Vb     = (u16*)(ws + 56 * MB);
  u16* ctxb   = xb;                    // reuse xb after QKV GEMM

  cvt_bf16_kernel<<<(M_ROWS * D_DIM / 4 + 255) / 256, 256, 0, stream>>>(x, xb, M_ROWS * D_DIM / 4);
  cvt_w_kernel<<<dim3(D_DIM * D_DIM / 4 / 256, 4), 256, 0, stream>>>(Wq, Wk, Wv, Wo, Wqkvb);

  gemm_qkv_kernel<<<dim3(3 * D_DIM / 128, M_ROWS / 128), 256, 0, stream>>>(
      xb, Wqkvb, bq, bk, bv, Qb, Kb, Vb);

  attn_kernel<<<dim3(NQB / 2, BATCH * NH), 256, 0, stream>>>(Qb, Kb, Vb, ctxb);

  gemm_out_kernel<<<dim3(D_DIM / 128, M_ROWS / 128), 256, 0, stream>>>(
      ctxb, Wob, bo, (float*)d_out);
}